// Round 7
// baseline (82666.028 us; speedup 1.0000x reference)
//
#include <hip/hip_runtime.h>
#include <hip/hip_bf16.h>
#include <hip/hip_cooperative_groups.h>
#include <cstdint>

namespace cg = cooperative_groups;

static constexpr int B_ = 256;
static constexpr int T_ = 512;
static constexpr int I_ = 64;
static constexpr int H_ = 512;
static constexpr int G_ = 4 * H_;          // 2048 gate columns (interleaved: col = 4*j + gate)
static constexpr int L_ = 4;
static constexpr int NSTEP = T_ + L_ - 1;  // 515 pipelined steps

// ---------- helpers ----------
__device__ __forceinline__ float bfu2f(unsigned short u) {
    return __uint_as_float(((unsigned int)u) << 16);
}
__device__ __forceinline__ void store_w(float* p, float v) { *p = v; }
__device__ __forceinline__ void store_w(__hip_bfloat16* p, float v) { *p = __float2bfloat16(v); }

__device__ __forceinline__ float4 loadw4(const float* p) { return *(const float4*)p; }
__device__ __forceinline__ float4 loadw4(const __hip_bfloat16* p) {
    const ushort4 u = *(const ushort4*)p;
    float4 f;
    f.x = bfu2f(u.x); f.y = bfu2f(u.y); f.z = bfu2f(u.z); f.w = bfu2f(u.w);
    return f;
}

// WT[k][4j+g] = (k<H) ? W_hh[g*H+j][k] : W_ih[g*H+j][k-H]
template <typename WO>
__global__ void prep_wt(const float* __restrict__ Whh_l,
                        const float* __restrict__ Wih_l,
                        int Kin, WO* __restrict__ WT)
{
    const size_t total = (size_t)(H_ + Kin) * G_;
    for (size_t idx = (size_t)blockIdx.x * blockDim.x + threadIdx.x; idx < total;
         idx += (size_t)gridDim.x * blockDim.x) {
        const int k   = (int)(idx >> 11);
        const int col = (int)(idx & 2047);
        const int j = col >> 2, g = col & 3;
        const int r = g * H_ + j;
        const float v = (k < H_) ? Whh_l[(size_t)r * H_ + k]
                                 : Wih_l[(size_t)r * Kin + (k - H_)];
        store_w(&WT[idx], v);
    }
}

__global__ void prep_bias(const float* __restrict__ bih, const float* __restrict__ bhh,
                          float* __restrict__ biasR)
{
    const int idx = blockIdx.x * blockDim.x + threadIdx.x;
    if (idx < L_ * G_) {
        const int l   = idx >> 11;
        const int col = idx & 2047;
        const int j = col >> 2, g = col & 3;
        const int r = l * G_ + g * H_ + j;
        biasR[idx] = bih[r] + bhh[r];
    }
}

__global__ void sentinel_fill(float* out, float v) { out[threadIdx.x] = v; }

// ---------- pipelined 4-layer LSTM, one persistent cooperative kernel ----------
// 256 blocks x 256 threads. blk>>6 = layer. Within layer: 16 batch-chunks x 4 hidden-chunks.
// Block = 16 batches x 128 units. Thread = unit j x 8 batches x 4 gates (32 acc, 8 c regs).
// bnd layout: (L, 2 parity, B, H) fp32. Step s: layer l computes t=s-l,
// reads own h(t-1) from bnd[l][(s+1)&1], x from bnd[l-1][(s+1)&1] (or global x for l=0),
// writes h(t) to bnd[l][s&1]. One grid.sync per step.
template <typename WT_T>
__global__ __launch_bounds__(256)
void lstm_pipe(const float* __restrict__ x,
               const WT_T* __restrict__ WT0, const WT_T* __restrict__ WT1,
               const WT_T* __restrict__ WT2, const WT_T* __restrict__ WT3,
               const float* __restrict__ biasR,
               float* __restrict__ bnd)
{
    cg::grid_group grid = cg::this_grid();
    __shared__ float cat[16][1024];      // 16 batches x (h[0:512] | x[512:1024]) = 64 KB

    const int tid = threadIdx.x;
    const int blk = blockIdx.x;
    const int l   = blk >> 6;            // layer 0..3
    const int w   = blk & 63;
    const int bc  = w & 15;              // batch chunk
    const int hc  = w >> 4;              // hidden chunk 0..3
    const int b0  = bc << 4;
    const int j   = (hc << 7) + (tid & 127);   // unit 0..511
    const int bh  = tid >> 7;                  // 0..1
    const int rbase = bh << 3;                 // rows rbase..rbase+7

    const WT_T* __restrict__ WTl = (l == 0) ? WT0 : (l == 1) ? WT1 : (l == 2) ? WT2 : WT3;
    const int K = (l == 0) ? (H_ + I_) : (H_ + H_);   // 576 or 1024

    const float4 bvec = *(const float4*)(biasR + l * G_ + (j << 2));

    float* __restrict__ bndl = bnd + (size_t)l * 2 * B_ * H_;
    const float* __restrict__ bndin = (l == 0) ? nullptr : (bnd + (size_t)(l - 1) * 2 * B_ * H_);

    float c[8];
#pragma unroll
    for (int r = 0; r < 8; ++r) c[r] = 0.f;

    for (int s = 0; s < NSTEP; ++s) {
        const int t = s - l;
        if (0 <= t && t < T_) {                 // block-uniform condition
            const int pr = (s + 1) & 1;         // parity written at step s-1 (zeros at t=0)
            const int pw = s & 1;

            // ---- stage own h(t-1): 16 x 512 fp32 ----
            {
                const float4* src = (const float4*)(bndl + (size_t)pr * B_ * H_ + (size_t)b0 * H_);
#pragma unroll
                for (int i = 0; i < 8; ++i) {
                    const int idx = tid + (i << 8);           // 0..2047
                    const int r = idx >> 7, kc = idx & 127;
                    *(float4*)(&cat[r][kc << 2]) = src[idx];
                }
            }
            // ---- stage x(t) ----
            if (l == 0) {
                // 16 rows x 64 floats = 256 float4 -> all 256 threads, one float4 each
                const int r = tid >> 4, cc = tid & 15;
                const float4* src = (const float4*)(x + ((size_t)(b0 + r) * T_ + t) * I_);
                *(float4*)(&cat[r][H_ + (cc << 2)]) = src[cc];
            } else {
                const float4* src = (const float4*)(bndin + (size_t)pr * B_ * H_ + (size_t)b0 * H_);
#pragma unroll
                for (int i = 0; i < 8; ++i) {
                    const int idx = tid + (i << 8);
                    const int r = idx >> 7, kc = idx & 127;
                    *(float4*)(&cat[r][H_ + (kc << 2)]) = src[idx];
                }
            }
            __syncthreads();

            // ---- GEMM: 8 batches x 4 gates, K-dim over concat(h, x) ----
            float a0[8], a1[8], a2[8], a3[8];
#pragma unroll
            for (int r = 0; r < 8; ++r) { a0[r] = a1[r] = a2[r] = a3[r] = 0.f; }

            for (int k = 0; k < K; k += 4) {
                const WT_T* wp = WTl + (size_t)k * G_ + (j << 2);
                const float4 w0 = loadw4(wp);
                const float4 w1 = loadw4(wp + G_);
                const float4 w2 = loadw4(wp + 2 * G_);
                const float4 w3 = loadw4(wp + 3 * G_);
#pragma unroll
                for (int r = 0; r < 8; ++r) {
                    const float4 hv = *(const float4*)(&cat[rbase + r][k]);  // wave-uniform broadcast
                    a0[r] = fmaf(w0.x, hv.x, a0[r]);
                    a0[r] = fmaf(w1.x, hv.y, a0[r]);
                    a0[r] = fmaf(w2.x, hv.z, a0[r]);
                    a0[r] = fmaf(w3.x, hv.w, a0[r]);
                    a1[r] = fmaf(w0.y, hv.x, a1[r]);
                    a1[r] = fmaf(w1.y, hv.y, a1[r]);
                    a1[r] = fmaf(w2.y, hv.z, a1[r]);
                    a1[r] = fmaf(w3.y, hv.w, a1[r]);
                    a2[r] = fmaf(w0.z, hv.x, a2[r]);
                    a2[r] = fmaf(w1.z, hv.y, a2[r]);
                    a2[r] = fmaf(w2.z, hv.z, a2[r]);
                    a2[r] = fmaf(w3.z, hv.w, a2[r]);
                    a3[r] = fmaf(w0.w, hv.x, a3[r]);
                    a3[r] = fmaf(w1.w, hv.y, a3[r]);
                    a3[r] = fmaf(w2.w, hv.z, a3[r]);
                    a3[r] = fmaf(w3.w, hv.w, a3[r]);
                }
            }

            // ---- gates -> c,h ; write h(t) ----
            float* outrow = bndl + (size_t)pw * B_ * H_;
#pragma unroll
            for (int r = 0; r < 8; ++r) {
                const float gi = a0[r] + bvec.x;
                const float gf = a1[r] + bvec.y;
                const float gg = a2[r] + bvec.z;
                const float go = a3[r] + bvec.w;
                const float iv = 1.f / (1.f + expf(-gi));
                const float fv = 1.f / (1.f + expf(-gf));
                const float gv = tanhf(gg);
                const float ov = 1.f / (1.f + expf(-go));
                c[r] = fv * c[r] + iv * gv;
                const float hv = ov * tanhf(c[r]);
                outrow[(size_t)(b0 + rbase + r) * H_ + j] = hv;
            }
        }
        grid.sync();
    }
}

// ---------- MLP head: reads h_3[T-1] from bnd[3][ (NSTEP-1)&1 ] ----------
__global__ __launch_bounds__(128)
void mlp_head(const float* __restrict__ h3,
              const float* __restrict__ W1, const float* __restrict__ b1,
              const float* __restrict__ W2, const float* __restrict__ b2,
              const float* __restrict__ W3, const float* __restrict__ b3,
              float* __restrict__ out)
{
    __shared__ float hl[H_];
    __shared__ float a1[128];
    __shared__ float a2[64];
    const int b = blockIdx.x, tid = threadIdx.x;
    const float* src = h3 + (size_t)b * H_;
    for (int k = tid; k < H_; k += 128) hl[k] = src[k];
    __syncthreads();
    {
        float s = b1[tid];
        const float* wr = W1 + (size_t)tid * H_;
        for (int k = 0; k < H_; ++k) s = fmaf(wr[k], hl[k], s);
        a1[tid] = fmaxf(s, 0.f);
    }
    __syncthreads();
    if (tid < 64) {
        float s = b2[tid];
        const float* wr = W2 + (tid << 7);
        for (int k = 0; k < 128; ++k) s = fmaf(wr[k], a1[k], s);
        a2[tid] = fmaxf(s, 0.f);
    }
    __syncthreads();
    if (tid < 64) {
        float v = W3[tid] * a2[tid];
        for (int off = 32; off; off >>= 1) v += __shfl_down(v, off);
        if (tid == 0) out[b] = v + b3[0];
    }
}

template <typename WT_T>
static hipError_t launch_pipe(const float* x, const WT_T* WT0, const WT_T* WT1,
                              const WT_T* WT2, const WT_T* WT3,
                              const float* biasR, float* bnd, hipStream_t stream)
{
    const float* xa = x;
    const WT_T* w0 = WT0; const WT_T* w1 = WT1; const WT_T* w2 = WT2; const WT_T* w3 = WT3;
    const float* br = biasR; float* bp = bnd;
    void* args[] = { (void*)&xa, (void*)&w0, (void*)&w1, (void*)&w2, (void*)&w3,
                     (void*)&br, (void*)&bp };
    return hipLaunchCooperativeKernel((void*)(lstm_pipe<WT_T>), dim3(256), dim3(256),
                                      args, 0, stream);
}

extern "C" void kernel_launch(void* const* d_in, const int* in_sizes, int n_in,
                              void* d_out, int out_size, void* d_ws, size_t ws_size,
                              hipStream_t stream)
{
    const float* x    = (const float*)d_in[0];
    const float* Wih0 = (const float*)d_in[1];
    const float* WihR = (const float*)d_in[2];
    const float* Whh  = (const float*)d_in[3];
    const float* bih  = (const float*)d_in[4];
    const float* bhh  = (const float*)d_in[5];
    const float* W1   = (const float*)d_in[6];
    const float* b1   = (const float*)d_in[7];
    const float* W2   = (const float*)d_in[8];
    const float* b2   = (const float*)d_in[9];
    const float* W3   = (const float*)d_in[10];
    const float* b3   = (const float*)d_in[11];
    float* out = (float*)d_out;

    const size_t WT0e = (size_t)(H_ + I_) * G_;   // 1,179,648
    const size_t WTe  = (size_t)(2 * H_) * G_;    // 2,097,152
    const size_t biasE = (size_t)L_ * G_;
    const size_t bndE  = (size_t)L_ * 2 * B_ * H_;          // 1,048,576 fp32 = 4 MB
    const size_t WL = (size_t)G_ * H_;                       // per-layer weight elems

    auto align256 = [](size_t v) { return (v + 255) & ~(size_t)255; };
    const size_t common = align256(biasE * 4) + align256(bndE * 4);
    const size_t need_f32  = align256(WT0e * 4) + 3 * align256(WTe * 4) + common;
    const size_t need_bf16 = align256(WT0e * 2) + 3 * align256(WTe * 2) + common;

    char* ws = (char*)d_ws;
    size_t off = 0;
    auto alloc = [&](size_t bytes) -> void* {
        void* p = ws + off;
        off = align256(off + bytes);
        return p;
    };

    if (ws_size < need_bf16) {
        sentinel_fill<<<1, 256, 0, stream>>>(out, -11111.0f);   // ws-too-small signature
        return;
    }

    const bool f32tier = (ws_size >= need_f32);
    const size_t we = f32tier ? 4 : 2;
    void* WT0 = alloc(WT0e * we);
    void* WT1 = alloc(WTe * we);
    void* WT2 = alloc(WTe * we);
    void* WT3 = alloc(WTe * we);
    float* biasR = (float*)alloc(biasE * 4);
    float* bnd   = (float*)alloc(bndE * 4);

    prep_bias<<<(L_ * G_ + 255) / 256, 256, 0, stream>>>(bih, bhh, biasR);
    hipMemsetAsync(bnd, 0, bndE * 4, stream);   // h(-1) = 0 for all layers/parities

    hipError_t rc;
    if (f32tier) {
        prep_wt<float><<<1024, 256, 0, stream>>>(Whh + 0 * WL, Wih0,          I_, (float*)WT0);
        prep_wt<float><<<1024, 256, 0, stream>>>(Whh + 1 * WL, WihR + 0 * WL, H_, (float*)WT1);
        prep_wt<float><<<1024, 256, 0, stream>>>(Whh + 2 * WL, WihR + 1 * WL, H_, (float*)WT2);
        prep_wt<float><<<1024, 256, 0, stream>>>(Whh + 3 * WL, WihR + 2 * WL, H_, (float*)WT3);
        rc = launch_pipe<float>(x, (const float*)WT0, (const float*)WT1,
                                (const float*)WT2, (const float*)WT3, biasR, bnd, stream);
    } else {
        prep_wt<__hip_bfloat16><<<1024, 256, 0, stream>>>(Whh + 0 * WL, Wih0,          I_, (__hip_bfloat16*)WT0);
        prep_wt<__hip_bfloat16><<<1024, 256, 0, stream>>>(Whh + 1 * WL, WihR + 0 * WL, H_, (__hip_bfloat16*)WT1);
        prep_wt<__hip_bfloat16><<<1024, 256, 0, stream>>>(Whh + 2 * WL, WihR + 1 * WL, H_, (__hip_bfloat16*)WT2);
        prep_wt<__hip_bfloat16><<<1024, 256, 0, stream>>>(Whh + 3 * WL, WihR + 2 * WL, H_, (__hip_bfloat16*)WT3);
        rc = launch_pipe<__hip_bfloat16>(x, (const __hip_bfloat16*)WT0, (const __hip_bfloat16*)WT1,
                                         (const __hip_bfloat16*)WT2, (const __hip_bfloat16*)WT3,
                                         biasR, bnd, stream);
    }
    if (rc != hipSuccess) {
        sentinel_fill<<<1, 256, 0, stream>>>(out, -22222.0f);   // coop-launch-failed signature
        return;
    }

    // h_3[T-1] lives at parity (NSTEP-1)&1 == 0
    const float* h3 = bnd + ((size_t)3 * 2 + ((NSTEP - 1) & 1)) * B_ * H_;
    mlp_head<<<256, 128, 0, stream>>>(h3, W1, b1, W2, b2, W3, b3, out);
}

// Round 8
// 67790.027 us; speedup vs baseline: 1.2194x; 1.2194x over previous
//
#include <hip/hip_runtime.h>
#include <hip/hip_bf16.h>
#include <hip/hip_cooperative_groups.h>
#include <cstdint>

namespace cg = cooperative_groups;

static constexpr int B_ = 256;
static constexpr int T_ = 512;
static constexpr int I_ = 64;
static constexpr int H_ = 512;
static constexpr int G_ = 4 * H_;          // 2048 gate columns (interleaved: col = 4*j + gate)
static constexpr int L_ = 4;
static constexpr int NSTEP = T_ + L_ - 1;  // 515 pipelined steps

// ---------- helpers ----------
__device__ __forceinline__ float bfu2f(unsigned short u) {
    return __uint_as_float(((unsigned int)u) << 16);
}
__device__ __forceinline__ void store_w(float* p, float v) { *p = v; }
__device__ __forceinline__ void store_w(__hip_bfloat16* p, float v) { *p = __float2bfloat16(v); }

__device__ __forceinline__ float4 loadw4(const float* p) { return *(const float4*)p; }
__device__ __forceinline__ float4 loadw4(const __hip_bfloat16* p) {
    const ushort4 u = *(const ushort4*)p;
    float4 f;
    f.x = bfu2f(u.x); f.y = bfu2f(u.y); f.z = bfu2f(u.z); f.w = bfu2f(u.w);
    return f;
}

// WT[k][4j+g] = (k<H) ? W_hh[g*H+j][k] : W_ih[g*H+j][k-H]
template <typename WO>
__global__ void prep_wt(const float* __restrict__ Whh_l,
                        const float* __restrict__ Wih_l,
                        int Kin, WO* __restrict__ WT)
{
    const size_t total = (size_t)(H_ + Kin) * G_;
    for (size_t idx = (size_t)blockIdx.x * blockDim.x + threadIdx.x; idx < total;
         idx += (size_t)gridDim.x * blockDim.x) {
        const int k   = (int)(idx >> 11);
        const int col = (int)(idx & 2047);
        const int j = col >> 2, g = col & 3;
        const int r = g * H_ + j;
        const float v = (k < H_) ? Whh_l[(size_t)r * H_ + k]
                                 : Wih_l[(size_t)r * Kin + (k - H_)];
        store_w(&WT[idx], v);
    }
}

__global__ void prep_bias(const float* __restrict__ bih, const float* __restrict__ bhh,
                          float* __restrict__ biasR)
{
    const int idx = blockIdx.x * blockDim.x + threadIdx.x;
    if (idx < L_ * G_) {
        const int l   = idx >> 11;
        const int col = idx & 2047;
        const int j = col >> 2, g = col & 3;
        const int r = l * G_ + g * H_ + j;
        biasR[idx] = bih[r] + bhh[r];
    }
}

__global__ void sentinel_fill(float* out, float v) { out[threadIdx.x] = v; }

// ---------- pipelined 4-layer LSTM, one persistent cooperative kernel ----------
// 256 blocks x 512 threads (8 waves/CU = 2 waves/SIMD for latency hiding).
//
// XCD-aware decomposition (assumes XCD = blockIdx % 8 round-robin, learn_hip m09):
//   xcd  = blk & 7          -> layer = xcd >> 1, half = xcd & 1
//   slot = blk >> 3 (0..31) -> hc = (half<<1) | (slot>>4), bc = slot & 15
// => layer l lives on XCDs {2l, 2l+1}; each XCD re-reads the SAME 2 hc weight
//    slices (<= 4 MB fp32) every step -> L2-resident weights.
//
// Block = 16 batches x 128 units. Thread = unit j x 4 batches x 4 gates.
// bnd layout: (L, 2 parity, B, H) fp32. Step s: layer l computes t=s-l,
// reads own h(t-1) from bnd[l][(s+1)&1], x from bnd[l-1][(s+1)&1] (or global x for l=0),
// writes h(t) to bnd[l][s&1]. One grid.sync per step.
template <typename WT_T>
__global__ __launch_bounds__(512)
void lstm_pipe(const float* __restrict__ x,
               const WT_T* __restrict__ WT0, const WT_T* __restrict__ WT1,
               const WT_T* __restrict__ WT2, const WT_T* __restrict__ WT3,
               const float* __restrict__ biasR,
               float* __restrict__ bnd)
{
    cg::grid_group grid = cg::this_grid();
    __shared__ float cat[16][1024];      // 16 batches x (h[0:512] | x[512:1024]) = 64 KB

    const int tid = threadIdx.x;
    const int blk = blockIdx.x;
    const int xcd  = blk & 7;
    const int slot = blk >> 3;                 // 0..31
    const int l    = xcd >> 1;                 // layer 0..3
    const int hc   = ((xcd & 1) << 1) | (slot >> 4);   // 0..3
    const int bc   = slot & 15;                // batch chunk
    const int b0   = bc << 4;
    const int j    = (hc << 7) + (tid & 127);  // unit 0..511
    const int bh   = tid >> 7;                 // 0..3
    const int rbase = bh << 2;                 // rows rbase..rbase+3

    const WT_T* __restrict__ WTl = (l == 0) ? WT0 : (l == 1) ? WT1 : (l == 2) ? WT2 : WT3;
    const int K = (l == 0) ? (H_ + I_) : (H_ + H_);   // 576 or 1024

    const float4 bvec = *(const float4*)(biasR + l * G_ + (j << 2));

    float* __restrict__ bndl = bnd + (size_t)l * 2 * B_ * H_;
    const float* __restrict__ bndin = (l == 0) ? nullptr : (bnd + (size_t)(l - 1) * 2 * B_ * H_);

    float c[4];
#pragma unroll
    for (int r = 0; r < 4; ++r) c[r] = 0.f;

    for (int s = 0; s < NSTEP; ++s) {
        const int t = s - l;
        if (0 <= t && t < T_) {                 // block-uniform condition
            const int pr = (s + 1) & 1;         // parity written at step s-1 (zeros at t=0)
            const int pw = s & 1;

            // ---- stage own h(t-1): 16 x 512 fp32 = 2048 float4, 512 threads x 4 ----
            {
                const float4* src = (const float4*)(bndl + (size_t)pr * B_ * H_ + (size_t)b0 * H_);
#pragma unroll
                for (int i = 0; i < 4; ++i) {
                    const int idx = tid + (i << 9);           // 0..2047
                    const int r = idx >> 7, kc = idx & 127;
                    *(float4*)(&cat[r][kc << 2]) = src[idx];
                }
            }
            // ---- stage x(t) ----
            if (l == 0) {
                // 16 rows x 64 floats = 256 float4
                if (tid < 256) {
                    const int r = tid >> 4, cc = tid & 15;
                    const float4* src = (const float4*)(x + ((size_t)(b0 + r) * T_ + t) * I_);
                    *(float4*)(&cat[r][H_ + (cc << 2)]) = src[cc];
                }
            } else {
                const float4* src = (const float4*)(bndin + (size_t)pr * B_ * H_ + (size_t)b0 * H_);
#pragma unroll
                for (int i = 0; i < 4; ++i) {
                    const int idx = tid + (i << 9);
                    const int r = idx >> 7, kc = idx & 127;
                    *(float4*)(&cat[r][H_ + (kc << 2)]) = src[idx];
                }
            }
            __syncthreads();

            // ---- GEMM: 4 batches x 4 gates, K-dim over concat(h, x) ----
            float a0[4], a1[4], a2[4], a3[4];
#pragma unroll
            for (int r = 0; r < 4; ++r) { a0[r] = a1[r] = a2[r] = a3[r] = 0.f; }

            for (int k = 0; k < K; k += 4) {
                const WT_T* wp = WTl + (size_t)k * G_ + (j << 2);
                const float4 w0 = loadw4(wp);
                const float4 w1 = loadw4(wp + G_);
                const float4 w2 = loadw4(wp + 2 * G_);
                const float4 w3 = loadw4(wp + 3 * G_);
#pragma unroll
                for (int r = 0; r < 4; ++r) {
                    const float4 hv = *(const float4*)(&cat[rbase + r][k]);  // wave-uniform broadcast
                    a0[r] = fmaf(w0.x, hv.x, a0[r]);
                    a0[r] = fmaf(w1.x, hv.y, a0[r]);
                    a0[r] = fmaf(w2.x, hv.z, a0[r]);
                    a0[r] = fmaf(w3.x, hv.w, a0[r]);
                    a1[r] = fmaf(w0.y, hv.x, a1[r]);
                    a1[r] = fmaf(w1.y, hv.y, a1[r]);
                    a1[r] = fmaf(w2.y, hv.z, a1[r]);
                    a1[r] = fmaf(w3.y, hv.w, a1[r]);
                    a2[r] = fmaf(w0.z, hv.x, a2[r]);
                    a2[r] = fmaf(w1.z, hv.y, a2[r]);
                    a2[r] = fmaf(w2.z, hv.z, a2[r]);
                    a2[r] = fmaf(w3.z, hv.w, a2[r]);
                    a3[r] = fmaf(w0.w, hv.x, a3[r]);
                    a3[r] = fmaf(w1.w, hv.y, a3[r]);
                    a3[r] = fmaf(w2.w, hv.z, a3[r]);
                    a3[r] = fmaf(w3.w, hv.w, a3[r]);
                }
            }

            // ---- gates -> c,h ; write h(t) ----
            float* outrow = bndl + (size_t)pw * B_ * H_;
#pragma unroll
            for (int r = 0; r < 4; ++r) {
                const float gi = a0[r] + bvec.x;
                const float gf = a1[r] + bvec.y;
                const float gg = a2[r] + bvec.z;
                const float go = a3[r] + bvec.w;
                const float iv = 1.f / (1.f + expf(-gi));
                const float fv = 1.f / (1.f + expf(-gf));
                const float gv = tanhf(gg);
                const float ov = 1.f / (1.f + expf(-go));
                c[r] = fv * c[r] + iv * gv;
                const float hv = ov * tanhf(c[r]);
                outrow[(size_t)(b0 + rbase + r) * H_ + j] = hv;
            }
        }
        grid.sync();
    }
}

// ---------- MLP head: reads h_3[T-1] from bnd[3][ (NSTEP-1)&1 ] ----------
__global__ __launch_bounds__(128)
void mlp_head(const float* __restrict__ h3,
              const float* __restrict__ W1, const float* __restrict__ b1,
              const float* __restrict__ W2, const float* __restrict__ b2,
              const float* __restrict__ W3, const float* __restrict__ b3,
              float* __restrict__ out)
{
    __shared__ float hl[H_];
    __shared__ float a1[128];
    __shared__ float a2[64];
    const int b = blockIdx.x, tid = threadIdx.x;
    const float* src = h3 + (size_t)b * H_;
    for (int k = tid; k < H_; k += 128) hl[k] = src[k];
    __syncthreads();
    {
        float s = b1[tid];
        const float* wr = W1 + (size_t)tid * H_;
        for (int k = 0; k < H_; ++k) s = fmaf(wr[k], hl[k], s);
        a1[tid] = fmaxf(s, 0.f);
    }
    __syncthreads();
    if (tid < 64) {
        float s = b2[tid];
        const float* wr = W2 + (tid << 7);
        for (int k = 0; k < 128; ++k) s = fmaf(wr[k], a1[k], s);
        a2[tid] = fmaxf(s, 0.f);
    }
    __syncthreads();
    if (tid < 64) {
        float v = W3[tid] * a2[tid];
        for (int off = 32; off; off >>= 1) v += __shfl_down(v, off);
        if (tid == 0) out[b] = v + b3[0];
    }
}

template <typename WT_T>
static hipError_t launch_pipe(const float* x, const WT_T* WT0, const WT_T* WT1,
                              const WT_T* WT2, const WT_T* WT3,
                              const float* biasR, float* bnd, hipStream_t stream)
{
    const float* xa = x;
    const WT_T* w0 = WT0; const WT_T* w1 = WT1; const WT_T* w2 = WT2; const WT_T* w3 = WT3;
    const float* br = biasR; float* bp = bnd;
    void* args[] = { (void*)&xa, (void*)&w0, (void*)&w1, (void*)&w2, (void*)&w3,
                     (void*)&br, (void*)&bp };
    return hipLaunchCooperativeKernel((void*)(lstm_pipe<WT_T>), dim3(256), dim3(512),
                                      args, 0, stream);
}

extern "C" void kernel_launch(void* const* d_in, const int* in_sizes, int n_in,
                              void* d_out, int out_size, void* d_ws, size_t ws_size,
                              hipStream_t stream)
{
    const float* x    = (const float*)d_in[0];
    const float* Wih0 = (const float*)d_in[1];
    const float* WihR = (const float*)d_in[2];
    const float* Whh  = (const float*)d_in[3];
    const float* bih  = (const float*)d_in[4];
    const float* bhh  = (const float*)d_in[5];
    const float* W1   = (const float*)d_in[6];
    const float* b1   = (const float*)d_in[7];
    const float* W2   = (const float*)d_in[8];
    const float* b2   = (const float*)d_in[9];
    const float* W3   = (const float*)d_in[10];
    const float* b3   = (const float*)d_in[11];
    float* out = (float*)d_out;

    const size_t WT0e = (size_t)(H_ + I_) * G_;   // 1,179,648
    const size_t WTe  = (size_t)(2 * H_) * G_;    // 2,097,152
    const size_t biasE = (size_t)L_ * G_;
    const size_t bndE  = (size_t)L_ * 2 * B_ * H_;          // 1,048,576 fp32 = 4 MB
    const size_t WL = (size_t)G_ * H_;                       // per-layer weight elems

    auto align256 = [](size_t v) { return (v + 255) & ~(size_t)255; };
    const size_t common = align256(biasE * 4) + align256(bndE * 4);
    const size_t need_f32  = align256(WT0e * 4) + 3 * align256(WTe * 4) + common;
    const size_t need_bf16 = align256(WT0e * 2) + 3 * align256(WTe * 2) + common;

    char* ws = (char*)d_ws;
    size_t off = 0;
    auto alloc = [&](size_t bytes) -> void* {
        void* p = ws + off;
        off = align256(off + bytes);
        return p;
    };

    if (ws_size < need_bf16) {
        sentinel_fill<<<1, 256, 0, stream>>>(out, -11111.0f);   // ws-too-small signature
        return;
    }

    const bool f32tier = (ws_size >= need_f32);
    const size_t we = f32tier ? 4 : 2;
    void* WT0 = alloc(WT0e * we);
    void* WT1 = alloc(WTe * we);
    void* WT2 = alloc(WTe * we);
    void* WT3 = alloc(WTe * we);
    float* biasR = (float*)alloc(biasE * 4);
    float* bnd   = (float*)alloc(bndE * 4);

    prep_bias<<<(L_ * G_ + 255) / 256, 256, 0, stream>>>(bih, bhh, biasR);
    hipMemsetAsync(bnd, 0, bndE * 4, stream);   // h(-1) = 0 for all layers/parities

    hipError_t rc;
    if (f32tier) {
        prep_wt<float><<<1024, 256, 0, stream>>>(Whh + 0 * WL, Wih0,          I_, (float*)WT0);
        prep_wt<float><<<1024, 256, 0, stream>>>(Whh + 1 * WL, WihR + 0 * WL, H_, (float*)WT1);
        prep_wt<float><<<1024, 256, 0, stream>>>(Whh + 2 * WL, WihR + 1 * WL, H_, (float*)WT2);
        prep_wt<float><<<1024, 256, 0, stream>>>(Whh + 3 * WL, WihR + 2 * WL, H_, (float*)WT3);
        rc = launch_pipe<float>(x, (const float*)WT0, (const float*)WT1,
                                (const float*)WT2, (const float*)WT3, biasR, bnd, stream);
    } else {
        prep_wt<__hip_bfloat16><<<1024, 256, 0, stream>>>(Whh + 0 * WL, Wih0,          I_, (__hip_bfloat16*)WT0);
        prep_wt<__hip_bfloat16><<<1024, 256, 0, stream>>>(Whh + 1 * WL, WihR + 0 * WL, H_, (__hip_bfloat16*)WT1);
        prep_wt<__hip_bfloat16><<<1024, 256, 0, stream>>>(Whh + 2 * WL, WihR + 1 * WL, H_, (__hip_bfloat16*)WT2);
        prep_wt<__hip_bfloat16><<<1024, 256, 0, stream>>>(Whh + 3 * WL, WihR + 2 * WL, H_, (__hip_bfloat16*)WT3);
        rc = launch_pipe<__hip_bfloat16>(x, (const __hip_bfloat16*)WT0, (const __hip_bfloat16*)WT1,
                                         (const __hip_bfloat16*)WT2, (const __hip_bfloat16*)WT3,
                                         biasR, bnd, stream);
    }
    if (rc != hipSuccess) {
        sentinel_fill<<<1, 256, 0, stream>>>(out, -22222.0f);   // coop-launch-failed signature
        return;
    }

    // h_3[T-1] lives at parity (NSTEP-1)&1 == 0
    const float* h3 = bnd + ((size_t)3 * 2 + ((NSTEP - 1) & 1)) * B_ * H_;
    mlp_head<<<256, 128, 0, stream>>>(h3, W1, b1, W2, b2, W3, b3, out);
}

// Round 9
// 40680.478 us; speedup vs baseline: 2.0321x; 1.6664x over previous
//
#include <hip/hip_runtime.h>
#include <hip/hip_bf16.h>
#include <hip/hip_cooperative_groups.h>
#include <cstdint>

namespace cg = cooperative_groups;

static constexpr int B_ = 256;
static constexpr int T_ = 512;
static constexpr int I_ = 64;
static constexpr int H_ = 512;
static constexpr int G_ = 4 * H_;          // 2048 gate cols, interleaved col = 4*j + g
static constexpr int L_ = 4;
static constexpr int NSTEP = T_ + L_ - 1;  // 515

typedef __attribute__((ext_vector_type(8))) short short8;   // 8 bf16 (4 VGPRs)
typedef __attribute__((ext_vector_type(4))) float f32x4;

// ---------- helpers ----------
__device__ __forceinline__ float bfu2f(unsigned short u) {
    return __uint_as_float(((unsigned int)u) << 16);
}
__device__ __forceinline__ unsigned short f2bfu(float v) {
    __hip_bfloat16 h = __float2bfloat16(v);   // RNE
    return *(unsigned short*)&h;
}

// ---------- weight prep: B-fragment layout, split hi/lo ----------
// For col n (0..2047), k (0..K-1):  w = (k<512) ? Whh[(g*512+j)][k] : Wih[(g*512+j)][k-512]
//   j = n>>2, g = n&3.  Frag: nt=n>>4, n16=n&15, kb=k>>5, bq=(k>>3)&3, kk=k&7,
//   lane = n16 + 16*bq, off = ((nt*NKB+kb)*64+lane)*8 + kk.
__global__ void prep_wtfrag(const float* __restrict__ Whh_l,
                            const float* __restrict__ Wih_l,
                            int Kin, int NKB,
                            unsigned short* __restrict__ WH,
                            unsigned short* __restrict__ WL)
{
    const size_t total = (size_t)(H_ + Kin) * G_;
    for (size_t idx = (size_t)blockIdx.x * blockDim.x + threadIdx.x; idx < total;
         idx += (size_t)gridDim.x * blockDim.x) {
        const int k = (int)(idx >> 11);
        const int n = (int)(idx & 2047);
        const int j = n >> 2, g = n & 3;
        const int r = g * H_ + j;
        const float w = (k < H_) ? Whh_l[(size_t)r * H_ + k]
                                 : Wih_l[(size_t)r * Kin + (k - H_)];
        const int nt = n >> 4, n16 = n & 15;
        const int kb = k >> 5, bq = (k >> 3) & 3, kk = k & 7;
        const size_t off = (((size_t)(nt * NKB + kb) << 6) + (n16 + (bq << 4)) << 3) + kk;
        const unsigned short hi = f2bfu(w);
        WH[off] = hi;
        WL[off] = f2bfu(w - bfu2f(hi));
    }
}

__global__ void prep_bias(const float* __restrict__ bih, const float* __restrict__ bhh,
                          float* __restrict__ biasR)
{
    const int idx = blockIdx.x * blockDim.x + threadIdx.x;
    if (idx < L_ * G_) {
        const int l   = idx >> 11;
        const int col = idx & 2047;
        const int j = col >> 2, g = col & 3;
        const int r = l * G_ + g * H_ + j;
        biasR[idx] = bih[r] + bhh[r];
    }
}

__global__ void sentinel_fill(float* out, float v) { out[threadIdx.x] = v; }

// ---------- pipelined 4-layer LSTM, MFMA split-bf16 ----------
// 256 blocks x 512 threads.  xcd=blk&7 -> layer=xcd>>1 (2 XCDs/layer, L2-resident weights).
// Block tile: M=16 batches x N=512 gate-cols, K = 16(own h) + {2|16}(input) kblocks of 32.
// 8 waves x 4 ntiles of 16 cols.  3 MFMAs per (kb,nt): wH*aH + wL*aH + wH*aL (fp32 acc).
// bnd (boundary h) is stored bf16 hi/lo in A-FRAGMENT layout:
//   bnd[l][parity][bc][kb(16)][lane(64)][kk(8)], elem offset (l*32+p*16+bc)*8192 + (kb*64+ln)*8+kk
// Step s: layer l computes t=s-l; reads own h(t-1) parity (s+1)&1, input from bnd[l-1] same
// parity (or global x for l=0, converted on the fly); writes h(t) parity s&1.  One grid.sync/step.
__global__ __launch_bounds__(512)
void lstm_pipe(const float* __restrict__ x,
               const unsigned short* __restrict__ WH0, const unsigned short* __restrict__ WL0,
               const unsigned short* __restrict__ WH1, const unsigned short* __restrict__ WL1,
               const unsigned short* __restrict__ WH2, const unsigned short* __restrict__ WL2,
               const unsigned short* __restrict__ WH3, const unsigned short* __restrict__ WL3,
               const float* __restrict__ biasR,
               unsigned short* __restrict__ bndH, unsigned short* __restrict__ bndL)
{
    cg::grid_group grid = cg::this_grid();
    __shared__ unsigned short ldsA[2][32][64][8];      // 64 KB; aliased by preact after MFMA

    const int tid = threadIdx.x;
    const int blk = blockIdx.x;
    const int xcd  = blk & 7;
    const int slot = blk >> 3;
    const int l    = xcd >> 1;
    const int hc   = ((xcd & 1) << 1) | (slot >> 4);
    const int bc   = slot & 15;
    const int b0   = bc << 4;
    const int lane = tid & 63;
    const int w8   = tid >> 6;                 // wave 0..7
    const int jl   = tid & 127;                // unit-local 0..127 (epilogue)
    const int rbase = (tid >> 7) << 2;         // batch rows rbase..rbase+3 (epilogue)

    const unsigned short* __restrict__ WHl = (l == 0) ? WH0 : (l == 1) ? WH1 : (l == 2) ? WH2 : WH3;
    const unsigned short* __restrict__ WLl = (l == 0) ? WL0 : (l == 1) ? WL1 : (l == 2) ? WL2 : WL3;
    const int NKB = (l == 0) ? 18 : 32;        // kblocks of 32 along concat K
    const int nkbS = (l == 0) ? 16 : 32;       // kblocks staged by frag-copy (l0 x is converted)

    const int j = (hc << 7) + jl;              // global unit 0..511
    const float4 bvec = *(const float4*)(biasR + l * G_ + (j << 2));
    const int kbj = j >> 5, bqj = (j >> 3) & 3, kkj = j & 7;

    const int ntg0 = (hc << 5) + (w8 << 2);    // wave's first global ntile (of 128)
    const unsigned short* __restrict__ pWH = WHl + (((size_t)ntg0 * NKB) << 9) + (lane << 3);
    const unsigned short* __restrict__ pWL = WLl + (((size_t)ntg0 * NKB) << 9) + (lane << 3);
    const int ntStride = NKB << 9;

    float c0 = 0.f, c1 = 0.f, c2 = 0.f, c3 = 0.f;

    for (int s = 0; s < NSTEP; ++s) {
        const int t = s - l;
        if (0 <= t && t < T_) {
            const int pr = (s + 1) & 1;
            const int pw = s & 1;
            const size_t rbOwn = ((size_t)l * 32 + pr * 16 + bc) * 8192;
            const size_t rbIn  = (l > 0) ? ((size_t)(l - 1) * 32 + pr * 16 + bc) * 8192 : 0;

            // ---- stage A fragments (uint4 frag-copy from bnd) ----
            const int per = nkbS << 6;
            for (int c_ = tid; c_ < (per << 1); c_ += 512) {
                const int sp = (c_ >= per) ? 1 : 0;
                const int c2_ = c_ - sp * per;
                const int kb = c2_ >> 6, ln = c2_ & 63;
                const unsigned short* bsrc = sp ? bndL : bndH;
                const size_t eo = (kb < 16)
                    ? rbOwn + ((size_t)((kb << 6) | ln) << 3)
                    : rbIn  + ((size_t)(((kb - 16) << 6) | ln) << 3);
                *(uint4*)&ldsA[sp][kb][ln][0] = *(const uint4*)(bsrc + eo);
            }
            // ---- layer 0: convert x(t) on the fly into frag layout ----
            if (l == 0) {
                for (int e = tid; e < 1024; e += 512) {
                    const int m = e >> 6, kx = e & 63;
                    const float v = x[((size_t)(b0 + m) * T_ + t) * I_ + kx];
                    const unsigned short hi = f2bfu(v);
                    const unsigned short lo = f2bfu(v - bfu2f(hi));
                    const int kb = 16 + (kx >> 5);
                    const int ln = m + (((kx >> 3) & 3) << 4);
                    const int kk = kx & 7;
                    ldsA[0][kb][ln][kk] = hi;
                    ldsA[1][kb][ln][kk] = lo;
                }
            }
            __syncthreads();

            // ---- MFMA: C[m][n] over K, split-bf16 (3 products) ----
            f32x4 C0 = {0.f, 0.f, 0.f, 0.f};
            f32x4 C1 = {0.f, 0.f, 0.f, 0.f};
            f32x4 C2 = {0.f, 0.f, 0.f, 0.f};
            f32x4 C3 = {0.f, 0.f, 0.f, 0.f};
#pragma unroll 2
            for (int kb = 0; kb < NKB; ++kb) {
                const short8 aH = *(const short8*)&ldsA[0][kb][lane][0];
                const short8 aL = *(const short8*)&ldsA[1][kb][lane][0];
                const int ko = kb << 9;
                const short8 bH0 = *(const short8*)(pWH + ko);
                const short8 bL0 = *(const short8*)(pWL + ko);
                const short8 bH1 = *(const short8*)(pWH + ko + ntStride);
                const short8 bL1 = *(const short8*)(pWL + ko + ntStride);
                const short8 bH2 = *(const short8*)(pWH + ko + 2 * ntStride);
                const short8 bL2 = *(const short8*)(pWL + ko + 2 * ntStride);
                const short8 bH3 = *(const short8*)(pWH + ko + 3 * ntStride);
                const short8 bL3 = *(const short8*)(pWL + ko + 3 * ntStride);
                C0 = __builtin_amdgcn_mfma_f32_16x16x32_bf16(aH, bH0, C0, 0, 0, 0);
                C1 = __builtin_amdgcn_mfma_f32_16x16x32_bf16(aH, bH1, C1, 0, 0, 0);
                C2 = __builtin_amdgcn_mfma_f32_16x16x32_bf16(aH, bH2, C2, 0, 0, 0);
                C3 = __builtin_amdgcn_mfma_f32_16x16x32_bf16(aH, bH3, C3, 0, 0, 0);
                C0 = __builtin_amdgcn_mfma_f32_16x16x32_bf16(aL, bH0, C0, 0, 0, 0);
                C1 = __builtin_amdgcn_mfma_f32_16x16x32_bf16(aL, bH1, C1, 0, 0, 0);
                C2 = __builtin_amdgcn_mfma_f32_16x16x32_bf16(aL, bH2, C2, 0, 0, 0);
                C3 = __builtin_amdgcn_mfma_f32_16x16x32_bf16(aL, bH3, C3, 0, 0, 0);
                C0 = __builtin_amdgcn_mfma_f32_16x16x32_bf16(aH, bL0, C0, 0, 0, 0);
                C1 = __builtin_amdgcn_mfma_f32_16x16x32_bf16(aH, bL1, C1, 0, 0, 0);
                C2 = __builtin_amdgcn_mfma_f32_16x16x32_bf16(aH, bL2, C2, 0, 0, 0);
                C3 = __builtin_amdgcn_mfma_f32_16x16x32_bf16(aH, bL3, C3, 0, 0, 0);
            }
            __syncthreads();   // all waves done reading ldsA

            // ---- bounce preact through LDS (alias of ldsA): [16][520] f32 ----
            float* pre = (float*)ldsA;
            {
                const int q = lane >> 4, n16 = lane & 15;
                const int colb = (w8 << 6) + n16;     // w8*64 + n16
#pragma unroll
                for (int r = 0; r < 4; ++r) {
                    pre[(q * 4 + r) * 520 + colb     ] = C0[r];
                    pre[(q * 4 + r) * 520 + colb + 16] = C1[r];
                    pre[(q * 4 + r) * 520 + colb + 32] = C2[r];
                    pre[(q * 4 + r) * 520 + colb + 48] = C3[r];
                }
            }
            __syncthreads();

            // ---- gates -> c,h ; write h(t) to bnd frag layout (bf16 hi/lo) ----
            const size_t wb = ((size_t)l * 32 + pw * 16 + bc) * 8192;
#pragma unroll
            for (int r = 0; r < 4; ++r) {
                const float4 pg = *(const float4*)&pre[(rbase + r) * 520 + (jl << 2)];
                const float gi = pg.x + bvec.x;
                const float gf = pg.y + bvec.y;
                const float gg = pg.z + bvec.z;
                const float go = pg.w + bvec.w;
                const float iv = 1.f / (1.f + expf(-gi));
                const float fv = 1.f / (1.f + expf(-gf));
                const float gv = tanhf(gg);
                const float ov = 1.f / (1.f + expf(-go));
                float& cr = (r == 0) ? c0 : (r == 1) ? c1 : (r == 2) ? c2 : c3;
                cr = fv * cr + iv * gv;
                const float hv = ov * tanhf(cr);
                const int m = rbase + r;
                const size_t eo = wb + ((size_t)((kbj << 6) | (m + (bqj << 4))) << 3) + kkj;
                const unsigned short hi = f2bfu(hv);
                bndH[eo] = hi;
                bndL[eo] = f2bfu(hv - bfu2f(hi));
            }
        }
        grid.sync();
    }
}

// ---------- MLP head: reads h_3[T-1] (parity 0) from bnd frag layout ----------
__global__ __launch_bounds__(128)
void mlp_head(const unsigned short* __restrict__ bndH, const unsigned short* __restrict__ bndL,
              const float* __restrict__ W1, const float* __restrict__ b1,
              const float* __restrict__ W2, const float* __restrict__ b2,
              const float* __restrict__ W3, const float* __restrict__ b3,
              float* __restrict__ out)
{
    __shared__ float hl[H_];
    __shared__ float a1[128];
    __shared__ float a2[64];
    const int b = blockIdx.x, tid = threadIdx.x;
    // h3[b][k]: l=3, parity 0 -> base (3*32 + 0*16 + bc)*8192
    {
        const size_t base = ((size_t)96 + (b >> 4)) * 8192;
        const int k0 = tid << 2;                   // 4 consecutive k per thread
        const int kb = k0 >> 5, bq = (k0 >> 3) & 3, kk0 = k0 & 7;
        const int ln = (b & 15) + (bq << 4);
        const size_t eo = base + ((size_t)((kb << 6) | ln) << 3) + kk0;
        const ushort4 vh = *(const ushort4*)(bndH + eo);
        const ushort4 vl = *(const ushort4*)(bndL + eo);
        hl[k0 + 0] = bfu2f(vh.x) + bfu2f(vl.x);
        hl[k0 + 1] = bfu2f(vh.y) + bfu2f(vl.y);
        hl[k0 + 2] = bfu2f(vh.z) + bfu2f(vl.z);
        hl[k0 + 3] = bfu2f(vh.w) + bfu2f(vl.w);
    }
    __syncthreads();
    {
        float s = b1[tid];
        const float* wr = W1 + (size_t)tid * H_;
        for (int k = 0; k < H_; ++k) s = fmaf(wr[k], hl[k], s);
        a1[tid] = fmaxf(s, 0.f);
    }
    __syncthreads();
    if (tid < 64) {
        float s = b2[tid];
        const float* wr = W2 + (tid << 7);
        for (int k = 0; k < 128; ++k) s = fmaf(wr[k], a1[k], s);
        a2[tid] = fmaxf(s, 0.f);
    }
    __syncthreads();
    if (tid < 64) {
        float v = W3[tid] * a2[tid];
        for (int off = 32; off; off >>= 1) v += __shfl_down(v, off);
        if (tid == 0) out[b] = v + b3[0];
    }
}

extern "C" void kernel_launch(void* const* d_in, const int* in_sizes, int n_in,
                              void* d_out, int out_size, void* d_ws, size_t ws_size,
                              hipStream_t stream)
{
    const float* x    = (const float*)d_in[0];
    const float* Wih0 = (const float*)d_in[1];
    const float* WihR = (const float*)d_in[2];
    const float* Whh  = (const float*)d_in[3];
    const float* bih  = (const float*)d_in[4];
    const float* bhh  = (const float*)d_in[5];
    const float* W1   = (const float*)d_in[6];
    const float* b1   = (const float*)d_in[7];
    const float* W2   = (const float*)d_in[8];
    const float* b2   = (const float*)d_in[9];
    const float* W3   = (const float*)d_in[10];
    const float* b3   = (const float*)d_in[11];
    float* out = (float*)d_out;

    const size_t W0e = (size_t)(H_ + I_) * G_;       // 1,179,648 elems (NKB=18)
    const size_t W1e = (size_t)(2 * H_) * G_;        // 2,097,152 elems (NKB=32)
    const size_t biasE = (size_t)L_ * G_;            // 8192
    const size_t bndE  = (size_t)L_ * 2 * 16 * 16 * 64 * 8;   // 1,048,576 elems per split

    auto align256 = [](size_t v) { return (v + 255) & ~(size_t)255; };
    const size_t need = 2 * align256(W0e * 2) + 6 * align256(W1e * 2)
                      + align256(biasE * 4) + 2 * align256(bndE * 2);

    char* ws = (char*)d_ws;
    size_t off = 0;
    auto alloc = [&](size_t bytes) -> void* {
        void* p = ws + off;
        off = align256(off + bytes);
        return p;
    };

    if (ws_size < need) {
        sentinel_fill<<<1, 256, 0, stream>>>(out, -11111.0f);
        return;
    }

    unsigned short* WH0 = (unsigned short*)alloc(W0e * 2);
    unsigned short* WL0 = (unsigned short*)alloc(W0e * 2);
    unsigned short* WH1 = (unsigned short*)alloc(W1e * 2);
    unsigned short* WL1 = (unsigned short*)alloc(W1e * 2);
    unsigned short* WH2 = (unsigned short*)alloc(W1e * 2);
    unsigned short* WL2 = (unsigned short*)alloc(W1e * 2);
    unsigned short* WH3 = (unsigned short*)alloc(W1e * 2);
    unsigned short* WL3 = (unsigned short*)alloc(W1e * 2);
    float* biasR = (float*)alloc(biasE * 4);
    unsigned short* bndH = (unsigned short*)alloc(bndE * 2);
    unsigned short* bndL = (unsigned short*)alloc(bndE * 2);

    const size_t WL_ = (size_t)G_ * H_;   // per-layer Whh/Wih stride (elems)
    prep_wtfrag<<<1024, 256, 0, stream>>>(Whh + 0 * WL_, Wih0,           I_, 18, WH0, WL0);
    prep_wtfrag<<<1024, 256, 0, stream>>>(Whh + 1 * WL_, WihR + 0 * WL_, H_, 32, WH1, WL1);
    prep_wtfrag<<<1024, 256, 0, stream>>>(Whh + 2 * WL_, WihR + 1 * WL_, H_, 32, WH2, WL2);
    prep_wtfrag<<<1024, 256, 0, stream>>>(Whh + 3 * WL_, WihR + 2 * WL_, H_, 32, WH3, WL3);
    prep_bias<<<(L_ * G_ + 255) / 256, 256, 0, stream>>>(bih, bhh, biasR);
    hipMemsetAsync(bndH, 0, bndE * 2, stream);
    hipMemsetAsync(bndL, 0, bndE * 2, stream);

    {
        const float* xa = x;
        const unsigned short *a0 = WH0, *a1 = WL0, *a2 = WH1, *a3 = WL1,
                             *a4 = WH2, *a5 = WL2, *a6 = WH3, *a7 = WL3;
        const float* br = biasR;
        unsigned short *bh = bndH, *bl = bndL;
        void* args[] = { (void*)&xa, (void*)&a0, (void*)&a1, (void*)&a2, (void*)&a3,
                         (void*)&a4, (void*)&a5, (void*)&a6, (void*)&a7,
                         (void*)&br, (void*)&bh, (void*)&bl };
        hipError_t rc = hipLaunchCooperativeKernel((void*)lstm_pipe, dim3(256), dim3(512),
                                                   args, 0, stream);
        if (rc != hipSuccess) {
            sentinel_fill<<<1, 256, 0, stream>>>(out, -22222.0f);
            return;
        }
    }

    mlp_head<<<256, 128, 0, stream>>>(bndH, bndL, W1, b1, W2, b2, W3, b3, out);
}

// Round 11
// 37376.047 us; speedup vs baseline: 2.2117x; 1.0884x over previous
//
#include <hip/hip_runtime.h>
#include <hip/hip_bf16.h>
#include <hip/hip_cooperative_groups.h>
#include <cstdint>

namespace cg = cooperative_groups;

static constexpr int B_ = 256;
static constexpr int T_ = 512;
static constexpr int I_ = 64;
static constexpr int H_ = 512;
static constexpr int G_ = 2048;            // gate cols, col = 4*j + g
static constexpr int L_ = 4;
static constexpr int NSTEP = T_ + L_ - 1;  // 515

typedef __attribute__((ext_vector_type(8))) short short8;   // 8 bf16
typedef __attribute__((ext_vector_type(4))) float f32x4;
typedef __attribute__((ext_vector_type(4))) unsigned int u32x4;  // nontemporal-compatible 16B

__device__ __forceinline__ float bfu2f(unsigned short u) {
    return __uint_as_float(((unsigned int)u) << 16);
}
__device__ __forceinline__ unsigned short f2bfu(float v) {
    __hip_bfloat16 h = __float2bfloat16(v);   // RNE
    return *(unsigned short*)&h;
}

// ---------- weight prep: per-(layer,hc)-slice B-frag layout, split hi/lo ----------
// Slice = 256 gate cols (hc = n>>8). Within slice: nt = (n&255)>>4, n16 = n&15.
// k: kb = k>>5, bq = (k>>3)&3, kk = k&7, lane = n16 + 16*bq.
// elem off = hc*S + ((nt*NKB + kb)*64 + lane)*8 + kk,  S = 16*NKB*512.
__global__ void prep_wtfrag(const float* __restrict__ Whh_l,
                            const float* __restrict__ Wih_l,
                            int Kin, int NKB,
                            unsigned short* __restrict__ WH,
                            unsigned short* __restrict__ WL)
{
    const size_t total = (size_t)(H_ + Kin) * G_;
    const size_t S = (size_t)16 * NKB * 512;
    for (size_t idx = (size_t)blockIdx.x * blockDim.x + threadIdx.x; idx < total;
         idx += (size_t)gridDim.x * blockDim.x) {
        const int k = (int)(idx >> 11);
        const int n = (int)(idx & 2047);
        const int j = n >> 2, g = n & 3;
        const int r = g * H_ + j;
        const float w = (k < H_) ? Whh_l[(size_t)r * H_ + k]
                                 : Wih_l[(size_t)r * Kin + (k - H_)];
        const int hc = n >> 8;
        const int c  = n & 255;
        const int nt = c >> 4, n16 = c & 15;
        const int kb = k >> 5, bq = (k >> 3) & 3, kk = k & 7;
        const size_t off = (size_t)hc * S
                         + ((size_t)(nt * NKB + kb) * 64 + (n16 + (bq << 4))) * 8 + kk;
        const unsigned short hi = f2bfu(w);
        WH[off] = hi;
        WL[off] = f2bfu(w - bfu2f(hi));
    }
}

__global__ void prep_bias(const float* __restrict__ bih, const float* __restrict__ bhh,
                          float* __restrict__ biasR)
{
    const int idx = blockIdx.x * blockDim.x + threadIdx.x;
    if (idx < L_ * G_) {
        const int l   = idx >> 11;
        const int col = idx & 2047;
        const int j = col >> 2, g = col & 3;
        const int r = l * G_ + g * H_ + j;
        biasR[idx] = bih[r] + bhh[r];
    }
}

__global__ void sentinel_fill(float* out, float v) { out[threadIdx.x] = v; }

// ---------- pipelined 4-layer LSTM, MFMA split-bf16, L2-exact XCD partition ----------
// 256 blocks x 1024 threads (16 waves/CU = 4/SIMD).
// Slice table: xcd = blk&7, slot = blk>>3, si = slot>>3 (0..3), bc = slot&7.
//   si==0 -> (l=0, hc=xcd); else b = 3*xcd + si-1 -> l = 1 + b/8, hc = b&7.
// => per-XCD weights = 0.59 + 3*1.05 = 3.74 MB <= 4 MB L2, read by 8 bc-blocks each.
// Block tile: M=32 batches x N=256 gate cols.  K processed in 2 LDS passes of 16 kb.
// Wave wv (0..15): mt = wv&1 (16-row half), ntiles {2*(wv>>1), +1}.  3 MFMA per (kb,nt).
// bnd h storage (bf16 hi/lo, A-frag layout): [l][parity][bc(8)][kb(16)][mt(2)][lane(64)][kk(8)]
//   elem off = ((l*2+p)*8 + bc)*16384 + ((kb*2+mt)*64 + lane)*8 + kk.
// Step s: layer l computes t = s-l; reads parity (s+1)&1, writes parity s&1; one grid.sync/step.
__global__ __launch_bounds__(1024)
void lstm_pipe(const float* __restrict__ x,
               const unsigned short* __restrict__ WH0, const unsigned short* __restrict__ WL0,
               const unsigned short* __restrict__ WH1, const unsigned short* __restrict__ WL1,
               const unsigned short* __restrict__ WH2, const unsigned short* __restrict__ WL2,
               const unsigned short* __restrict__ WH3, const unsigned short* __restrict__ WL3,
               const float* __restrict__ biasR,
               unsigned short* __restrict__ bndH, unsigned short* __restrict__ bndL)
{
    cg::grid_group grid = cg::this_grid();
    __shared__ unsigned short ldsA[2][16][2][64][8];   // 64 KB; aliased by preact

    const int tid = threadIdx.x;
    const int blk = blockIdx.x;
    const int xcd  = blk & 7;
    const int slot = blk >> 3;
    const int si   = slot >> 3;          // slice index within XCD
    const int bc   = slot & 7;           // batch chunk (32 rows)
    int l, hc;
    if (si == 0) { l = 0; hc = xcd; }
    else { const int b = 3 * xcd + (si - 1); l = 1 + (b >> 3); hc = b & 7; }
    const int b0 = bc << 5;

    const int lane = tid & 63;
    const int wv   = tid >> 6;           // 0..15
    const int mt   = wv & 1;
    const int ntp  = wv >> 1;            // 0..7

    const unsigned short* __restrict__ WHl = (l == 0) ? WH0 : (l == 1) ? WH1 : (l == 2) ? WH2 : WH3;
    const unsigned short* __restrict__ WLl = (l == 0) ? WL0 : (l == 1) ? WL1 : (l == 2) ? WL2 : WL3;
    const int NKB = (l == 0) ? 18 : 32;
    const size_t S = (size_t)16 * NKB * 512;

    const size_t woff = (size_t)hc * S + (size_t)(2 * ntp) * NKB * 512 + (size_t)lane * 8;
    const unsigned short* __restrict__ pH0 = WHl + woff;
    const unsigned short* __restrict__ pL0 = WLl + woff;
    const size_t ntS = (size_t)NKB * 512;   // ntile stride

    // epilogue mapping: thread -> unit jl = lane, rows m = 2*wv + {0,1}
    const int jl = lane;
    const int jg = (hc << 6) + jl;
    const float4 bvec = *(const float4*)(biasR + l * G_ + (jg << 2));
    const int kbw = (hc << 1) + (jl >> 5);
    const int bqw = (jl >> 3) & 3;
    const int kkw = jl & 7;

    float cst[2] = {0.f, 0.f};

    for (int s = 0; s < NSTEP; ++s) {
        const int t = s - l;
        if (0 <= t && t < T_) {
            const int pr = (s + 1) & 1;
            const int pw = s & 1;
            const size_t rbOwn = ((size_t)(l * 2 + pr) * 8 + bc) * 16384;
            const size_t rbIn  = (l > 0) ? ((size_t)((l - 1) * 2 + pr) * 8 + bc) * 16384 : 0;

            f32x4 C0 = {0.f, 0.f, 0.f, 0.f};
            f32x4 C1 = {0.f, 0.f, 0.f, 0.f};

            auto mfma_pass = [&](int kstart, int ncnt) {
                const size_t kb0 = (size_t)kstart << 9;   // *512 elems
                short8 cH0 = *(const short8*)(pH0 + kb0);
                short8 cL0 = *(const short8*)(pL0 + kb0);
                short8 cH1 = *(const short8*)(pH0 + ntS + kb0);
                short8 cL1 = *(const short8*)(pL0 + ntS + kb0);
                for (int kbl = 0; kbl < ncnt; ++kbl) {
                    const int kn = (kbl + 1 < ncnt) ? kbl + 1 : kbl;
                    const size_t ko = kb0 + ((size_t)kn << 9);
                    const short8 nH0 = *(const short8*)(pH0 + ko);
                    const short8 nL0 = *(const short8*)(pL0 + ko);
                    const short8 nH1 = *(const short8*)(pH0 + ntS + ko);
                    const short8 nL1 = *(const short8*)(pL0 + ntS + ko);
                    const short8 aH = *(const short8*)&ldsA[0][kbl][mt][lane][0];
                    const short8 aL = *(const short8*)&ldsA[1][kbl][mt][lane][0];
                    C0 = __builtin_amdgcn_mfma_f32_16x16x32_bf16(aH, cH0, C0, 0, 0, 0);
                    C0 = __builtin_amdgcn_mfma_f32_16x16x32_bf16(aL, cH0, C0, 0, 0, 0);
                    C0 = __builtin_amdgcn_mfma_f32_16x16x32_bf16(aH, cL0, C0, 0, 0, 0);
                    C1 = __builtin_amdgcn_mfma_f32_16x16x32_bf16(aH, cH1, C1, 0, 0, 0);
                    C1 = __builtin_amdgcn_mfma_f32_16x16x32_bf16(aL, cH1, C1, 0, 0, 0);
                    C1 = __builtin_amdgcn_mfma_f32_16x16x32_bf16(aH, cL1, C1, 0, 0, 0);
                    cH0 = nH0; cL0 = nL0; cH1 = nH1; cL1 = nL1;
                }
            };

            // ---- pass 1: stage own h(t-1) (kb 0..15), 4096 x 16B ----
            {
                u32x4* dst = (u32x4*)&ldsA[0][0][0][0][0];
#pragma unroll
                for (int i = 0; i < 4; ++i) {
                    const int f = tid + (i << 10);
                    const int spl = f >> 11, rr = f & 2047;
                    const unsigned short* src = (spl ? bndL : bndH) + rbOwn + ((size_t)rr << 3);
                    dst[f] = __builtin_nontemporal_load(reinterpret_cast<const u32x4*>(src));
                }
            }
            __syncthreads();
            mfma_pass(0, 16);
            __syncthreads();

            // ---- pass 2: stage input (kb 16..31 global -> slots 0..) ----
            if (l == 0) {
                // x(t): 32 batches x 64 features, convert + split on the fly
#pragma unroll
                for (int i = 0; i < 2; ++i) {
                    const int e = tid + (i << 10);
                    const int m = e >> 6, kx = e & 63;
                    const float v = __builtin_nontemporal_load(
                        x + ((size_t)(b0 + m) * T_ + t) * I_ + kx);
                    const unsigned short hi = f2bfu(v);
                    const unsigned short lo = f2bfu(v - bfu2f(hi));
                    const int mtt = m >> 4, m16 = m & 15;
                    const int kbl = kx >> 5, bq = (kx >> 3) & 3, kk = kx & 7;
                    ldsA[0][kbl][mtt][m16 + (bq << 4)][kk] = hi;
                    ldsA[1][kbl][mtt][m16 + (bq << 4)][kk] = lo;
                }
            } else {
                u32x4* dst = (u32x4*)&ldsA[0][0][0][0][0];
#pragma unroll
                for (int i = 0; i < 4; ++i) {
                    const int f = tid + (i << 10);
                    const int spl = f >> 11, rr = f & 2047;
                    const unsigned short* src = (spl ? bndL : bndH) + rbIn + ((size_t)rr << 3);
                    dst[f] = __builtin_nontemporal_load(reinterpret_cast<const u32x4*>(src));
                }
            }
            __syncthreads();
            mfma_pass(16, (l == 0) ? 2 : 16);
            __syncthreads();

            // ---- preact bounce through LDS (alias): pre[32][264] f32 ----
            float* pre = (float*)&ldsA[0][0][0][0][0];
            {
                const int q = lane >> 4, n16 = lane & 15;
                const int row0 = (mt << 4) + (q << 2);
                const int col0 = (ntp << 5) + n16;
#pragma unroll
                for (int r = 0; r < 4; ++r) {
                    pre[(row0 + r) * 264 + col0]      = C0[r];
                    pre[(row0 + r) * 264 + col0 + 16] = C1[r];
                }
            }
            __syncthreads();

            // ---- gates -> c,h ; write h(t) to bnd (bf16 hi/lo, frag layout) ----
            const size_t wb = ((size_t)(l * 2 + pw) * 8 + bc) * 16384;
#pragma unroll
            for (int r = 0; r < 2; ++r) {
                const int m = (wv << 1) + r;
                const float4 pg = *(const float4*)&pre[m * 264 + (jl << 2)];
                const float gi = pg.x + bvec.x;
                const float gf = pg.y + bvec.y;
                const float gg = pg.z + bvec.z;
                const float go = pg.w + bvec.w;
                const float iv = 1.f / (1.f + expf(-gi));
                const float fv = 1.f / (1.f + expf(-gf));
                const float gv = tanhf(gg);
                const float ov = 1.f / (1.f + expf(-go));
                cst[r] = fv * cst[r] + iv * gv;
                const float hv = ov * tanhf(cst[r]);
                const int mtt = m >> 4, m16 = m & 15;
                const size_t eo = wb + ((size_t)((kbw << 1) + mtt) * 64 + (m16 + (bqw << 4))) * 8 + kkw;
                const unsigned short hi = f2bfu(hv);
                __builtin_nontemporal_store(hi, bndH + eo);
                __builtin_nontemporal_store(f2bfu(hv - bfu2f(hi)), bndL + eo);
            }
        }
        grid.sync();
    }
}

// ---------- MLP head: reads h_3[T-1] (parity 0) from bnd frag layout ----------
__global__ __launch_bounds__(128)
void mlp_head(const unsigned short* __restrict__ bndH, const unsigned short* __restrict__ bndL,
              const float* __restrict__ W1, const float* __restrict__ b1,
              const float* __restrict__ W2, const float* __restrict__ b2,
              const float* __restrict__ W3, const float* __restrict__ b3,
              float* __restrict__ out)
{
    __shared__ float hl[H_];
    __shared__ float a1[128];
    __shared__ float a2[64];
    const int b = blockIdx.x, tid = threadIdx.x;
    {
        const int bc = b >> 5, m = b & 31;
        const int mtt = m >> 4, m16 = m & 15;
        const size_t base = ((size_t)48 + bc) * 16384;   // (3*2+0)*8 + bc
        const int k0 = tid << 2;
        const int kb = k0 >> 5, bq = (k0 >> 3) & 3, kk0 = k0 & 7;
        const size_t eo = base + ((size_t)((kb << 1) + mtt) * 64 + (m16 + (bq << 4))) * 8 + kk0;
        const ushort4 vh = *(const ushort4*)(bndH + eo);
        const ushort4 vl = *(const ushort4*)(bndL + eo);
        hl[k0 + 0] = bfu2f(vh.x) + bfu2f(vl.x);
        hl[k0 + 1] = bfu2f(vh.y) + bfu2f(vl.y);
        hl[k0 + 2] = bfu2f(vh.z) + bfu2f(vl.z);
        hl[k0 + 3] = bfu2f(vh.w) + bfu2f(vl.w);
    }
    __syncthreads();
    {
        float s = b1[tid];
        const float* wr = W1 + (size_t)tid * H_;
        for (int k = 0; k < H_; ++k) s = fmaf(wr[k], hl[k], s);
        a1[tid] = fmaxf(s, 0.f);
    }
    __syncthreads();
    if (tid < 64) {
        float s = b2[tid];
        const float* wr = W2 + (tid << 7);
        for (int k = 0; k < 128; ++k) s = fmaf(wr[k], a1[k], s);
        a2[tid] = fmaxf(s, 0.f);
    }
    __syncthreads();
    if (tid < 64) {
        float v = W3[tid] * a2[tid];
        for (int off = 32; off; off >>= 1) v += __shfl_down(v, off);
        if (tid == 0) out[b] = v + b3[0];
    }
}

extern "C" void kernel_launch(void* const* d_in, const int* in_sizes, int n_in,
                              void* d_out, int out_size, void* d_ws, size_t ws_size,
                              hipStream_t stream)
{
    const float* x    = (const float*)d_in[0];
    const float* Wih0 = (const float*)d_in[1];
    const float* WihR = (const float*)d_in[2];
    const float* Whh  = (const float*)d_in[3];
    const float* bih  = (const float*)d_in[4];
    const float* bhh  = (const float*)d_in[5];
    const float* W1   = (const float*)d_in[6];
    const float* b1   = (const float*)d_in[7];
    const float* W2   = (const float*)d_in[8];
    const float* b2   = (const float*)d_in[9];
    const float* W3   = (const float*)d_in[10];
    const float* b3   = (const float*)d_in[11];
    float* out = (float*)d_out;

    const size_t W0e = (size_t)(H_ + I_) * G_;       // 1,179,648 elems (NKB=18)
    const size_t W1e = (size_t)(2 * H_) * G_;        // 2,097,152 elems (NKB=32)
    const size_t biasE = (size_t)L_ * G_;            // 8192
    const size_t bndE  = (size_t)64 * 16384;         // 1,048,576 elems per split

    auto align256 = [](size_t v) { return (v + 255) & ~(size_t)255; };
    const size_t need = 2 * align256(W0e * 2) + 6 * align256(W1e * 2)
                      + align256(biasE * 4) + 2 * align256(bndE * 2);

    char* ws = (char*)d_ws;
    size_t off = 0;
    auto alloc = [&](size_t bytes) -> void* {
        void* p = ws + off;
        off = align256(off + bytes);
        return p;
    };

    if (ws_size < need) {
        sentinel_fill<<<1, 256, 0, stream>>>(out, -11111.0f);
        return;
    }

    unsigned short* WH0 = (unsigned short*)alloc(W0e * 2);
    unsigned short* WL0 = (unsigned short*)alloc(W0e * 2);
    unsigned short* WH1 = (unsigned short*)alloc(W1e * 2);
    unsigned short* WL1 = (unsigned short*)alloc(W1e * 2);
    unsigned short* WH2 = (unsigned short*)alloc(W1e * 2);
    unsigned short* WL2 = (unsigned short*)alloc(W1e * 2);
    unsigned short* WH3 = (unsigned short*)alloc(W1e * 2);
    unsigned short* WL3 = (unsigned short*)alloc(W1e * 2);
    float* biasR = (float*)alloc(biasE * 4);
    unsigned short* bndH = (unsigned short*)alloc(bndE * 2);
    unsigned short* bndL = (unsigned short*)alloc(bndE * 2);

    const size_t WL_ = (size_t)G_ * H_;
    prep_wtfrag<<<1024, 256, 0, stream>>>(Whh + 0 * WL_, Wih0,           I_, 18, WH0, WL0);
    prep_wtfrag<<<1024, 256, 0, stream>>>(Whh + 1 * WL_, WihR + 0 * WL_, H_, 32, WH1, WL1);
    prep_wtfrag<<<1024, 256, 0, stream>>>(Whh + 2 * WL_, WihR + 1 * WL_, H_, 32, WH2, WL2);
    prep_wtfrag<<<1024, 256, 0, stream>>>(Whh + 3 * WL_, WihR + 2 * WL_, H_, 32, WH3, WL3);
    prep_bias<<<(L_ * G_ + 255) / 256, 256, 0, stream>>>(bih, bhh, biasR);
    (void)hipMemsetAsync(bndH, 0, bndE * 2, stream);
    (void)hipMemsetAsync(bndL, 0, bndE * 2, stream);

    {
        const float* xa = x;
        const unsigned short *a0 = WH0, *a1 = WL0, *a2 = WH1, *a3 = WL1,
                             *a4 = WH2, *a5 = WL2, *a6 = WH3, *a7 = WL3;
        const float* br = biasR;
        unsigned short *bh = bndH, *bl = bndL;
        void* args[] = { (void*)&xa, (void*)&a0, (void*)&a1, (void*)&a2, (void*)&a3,
                         (void*)&a4, (void*)&a5, (void*)&a6, (void*)&a7,
                         (void*)&br, (void*)&bh, (void*)&bl };
        hipError_t rc = hipLaunchCooperativeKernel((void*)lstm_pipe, dim3(256), dim3(1024),
                                                   args, 0, stream);
        if (rc != hipSuccess) {
            sentinel_fill<<<1, 256, 0, stream>>>(out, -22222.0f);
            return;
        }
    }

    mlp_head<<<256, 128, 0, stream>>>(bndH, bndL, W1, b1, W2, b2, W3, b3, out);
}

// Round 12
// 22069.164 us; speedup vs baseline: 3.7458x; 1.6936x over previous
//
#include <hip/hip_runtime.h>
#include <hip/hip_bf16.h>
#include <hip/hip_cooperative_groups.h>
#include <cstdint>

namespace cg = cooperative_groups;

static constexpr int B_ = 256;
static constexpr int T_ = 512;
static constexpr int I_ = 64;
static constexpr int H_ = 512;
static constexpr int G_ = 2048;            // gate cols, col = 4*j + g
static constexpr int L_ = 4;
static constexpr int NSTEP = T_ + L_ - 1;  // 515

typedef __attribute__((ext_vector_type(8))) short short8;   // 8 bf16
typedef __attribute__((ext_vector_type(4))) float f32x4;
typedef __attribute__((ext_vector_type(4))) unsigned int u32x4;

__device__ __forceinline__ float bfu2f(unsigned short u) {
    return __uint_as_float(((unsigned int)u) << 16);
}
__device__ __forceinline__ unsigned short f2bfu(float v) {
    __hip_bfloat16 h = __float2bfloat16(v);   // RNE
    return *(unsigned short*)&h;
}

// ---------- weight prep: per-(layer, 32-col slice) B-frag layout, split hi/lo ----------
// n (0..2047): ns = n>>5 (slice), ntl = (n>>4)&1 (ntile in slice), n16 = n&15.
// k: kb = k>>5, bq = (k>>3)&3, kk = k&7, lane = n16 + 16*bq.
// elem off = ns*Sl + ((ntl*NKB + kb)*64 + lane)*8 + kk,  Sl = 2*NKB*512.
__global__ void prep_wtfrag(const float* __restrict__ Whh_l,
                            const float* __restrict__ Wih_l,
                            int Kin, int NKB,
                            unsigned short* __restrict__ WH,
                            unsigned short* __restrict__ WL)
{
    const size_t total = (size_t)(H_ + Kin) * G_;
    const size_t Sl = (size_t)2 * NKB * 512;
    for (size_t idx = (size_t)blockIdx.x * blockDim.x + threadIdx.x; idx < total;
         idx += (size_t)gridDim.x * blockDim.x) {
        const int k = (int)(idx >> 11);
        const int n = (int)(idx & 2047);
        const int j = n >> 2, g = n & 3;
        const int r = g * H_ + j;
        const float w = (k < H_) ? Whh_l[(size_t)r * H_ + k]
                                 : Wih_l[(size_t)r * Kin + (k - H_)];
        const int ns = n >> 5, ntl = (n >> 4) & 1, n16 = n & 15;
        const int kb = k >> 5, bq = (k >> 3) & 3, kk = k & 7;
        const size_t off = (size_t)ns * Sl
                         + ((size_t)(ntl * NKB + kb) * 64 + (n16 + (bq << 4))) * 8 + kk;
        const unsigned short hi = f2bfu(w);
        WH[off] = hi;
        WL[off] = f2bfu(w - bfu2f(hi));
    }
}

__global__ void prep_bias(const float* __restrict__ bih, const float* __restrict__ bhh,
                          float* __restrict__ biasR)
{
    const int idx = blockIdx.x * blockDim.x + threadIdx.x;
    if (idx < L_ * G_) {
        const int l   = idx >> 11;
        const int col = idx & 2047;
        const int j = col >> 2, g = col & 3;
        const int r = l * G_ + g * H_ + j;
        biasR[idx] = bih[r] + bhh[r];
    }
}

__global__ void sentinel_fill(float* out, float v) { out[threadIdx.x] = v; }

// ---------- pipelined 4-layer LSTM: LDS-resident weights ----------
// 256 blocks x 1024 threads, 128 KB dynamic LDS -> 1 block/CU guaranteed.
// Block = (l = blk>>6, cs = blk&63): owns gate cols [cs*32, cs*32+32) = units cs*8..cs*8+7,
// weights for full K held in LDS (copied once; grid.sync L2 invalidation can't evict LDS).
// Per step: C[M=256][N=32]; wave wv: m-tile rows (wv>>1)*32 + (wv&1)*16 + m16.
// A-frags (h hi/lo) loaded straight from bnd global (1KB coalesced per load); no barriers
// inside a step; 4-gate gather via in-register 4x4 shfl_xor transpose.
// bnd layout (unchanged): [l][parity][bc8][kb16][mt2][lane64][kk8],
//   elem off = ((l*2+p)*8 + bc)*16384 + kb*1024 + mt*512 + lane*8 + kk.
__global__ __launch_bounds__(1024, 4)
void lstm_pipe(const float* __restrict__ x,
               const unsigned short* __restrict__ WH0, const unsigned short* __restrict__ WL0,
               const unsigned short* __restrict__ WH1, const unsigned short* __restrict__ WL1,
               const unsigned short* __restrict__ WH2, const unsigned short* __restrict__ WL2,
               const unsigned short* __restrict__ WH3, const unsigned short* __restrict__ WL3,
               const float* __restrict__ biasR,
               unsigned short* __restrict__ bndH, unsigned short* __restrict__ bndL)
{
    cg::grid_group grid = cg::this_grid();
    extern __shared__ unsigned short wgt[];   // [split2][ntl2][kb32][lane64][kk8] = 131072 B

    const int tid = threadIdx.x;
    const int blk = blockIdx.x;
    const int l   = blk >> 6;
    const int cs  = blk & 63;
    const int lane = tid & 63;
    const int wv   = tid >> 6;           // 0..15
    const int bcw  = wv >> 1;            // batch chunk (32 rows)
    const int mtw  = wv & 1;

    const unsigned short* __restrict__ WHl = (l == 0) ? WH0 : (l == 1) ? WH1 : (l == 2) ? WH2 : WH3;
    const unsigned short* __restrict__ WLl = (l == 0) ? WL0 : (l == 1) ? WL1 : (l == 2) ? WL2 : WL3;
    const int NKB = (l == 0) ? 18 : 32;

    // ---- one-time: copy this block's weight slice into LDS ----
    {
        const size_t gb = (size_t)cs * (2 * NKB * 512);
        const int chunks = 2 * NKB * 64;              // 8-elem chunks per split
        for (int c = tid; c < chunks; c += 1024) {
            const int ntl = c / (NKB * 64);
            const int r   = c - ntl * (NKB * 64);
            const int kb  = r >> 6, ln = r & 63;
            const size_t so = gb + ((size_t)(ntl * NKB + kb) * 64 + ln) * 8;
            const int dof = ((ntl * 32 + kb) * 64 + ln) * 8;
            *(u32x4*)&wgt[dof]         = *(const u32x4*)(WHl + so);
            *(u32x4*)&wgt[32768 + dof] = *(const u32x4*)(WLl + so);
        }
    }
    __syncthreads();

    // epilogue mapping (fixed per thread): after transpose, lane owns
    // row = bcw*32 + mtw*16 + (lane>>4)*4 + (lane&3), units u0 = (lane&15)>>2 and u0+4.
    const int dl  = lane & 3;
    const int u0  = (lane & 15) >> 2;
    const int row = bcw * 32 + mtw * 16 + ((lane >> 4) << 2) + dl;
    const int j0  = cs * 8 + u0;
    const int j1  = j0 + 4;
    const float4 bias0 = *(const float4*)(biasR + l * G_ + (j0 << 2));
    const float4 bias1 = *(const float4*)(biasR + l * G_ + (j1 << 2));
    const int bc2 = row >> 5, mt2 = (row >> 4) & 1, m16r = row & 15;
    auto h_eo = [&](int j) -> size_t {
        return (size_t)(j >> 5) * 1024 + (size_t)mt2 * 512
             + (size_t)(m16r + (((j >> 3) & 3) << 4)) * 8 + (j & 7);
    };
    const size_t eo0 = h_eo(j0), eo1 = h_eo(j1);

    auto xpose = [&](f32x4& v) {
        float t0 = __shfl_xor(v[1], 1);
        float t1 = __shfl_xor(v[0], 1);
        float t2 = __shfl_xor(v[3], 1);
        float t3 = __shfl_xor(v[2], 1);
        if (dl & 1) { v[0] = t0; v[2] = t2; } else { v[1] = t1; v[3] = t3; }
        float s0 = __shfl_xor(v[2], 2);
        float s1 = __shfl_xor(v[3], 2);
        float s2 = __shfl_xor(v[0], 2);
        float s3 = __shfl_xor(v[1], 2);
        if (dl & 2) { v[0] = s0; v[1] = s1; } else { v[2] = s2; v[3] = s3; }
    };

    float c0 = 0.f, c1 = 0.f;

    for (int s = 0; s < NSTEP; ++s) {
        const int t = s - l;
        if (0 <= t && t < T_) {
            const int pr = (s + 1) & 1;
            const int pw = s & 1;
            const size_t ebOwn = ((size_t)(l * 2 + pr) * 8 + bcw) * 16384
                               + (size_t)mtw * 512 + (size_t)lane * 8;

            f32x4 C0 = {0.f, 0.f, 0.f, 0.f};
            f32x4 C1 = {0.f, 0.f, 0.f, 0.f};

            // ---- own h(t-1): kb slots 0..15 ----
            {
                const unsigned short* aH_ = bndH + ebOwn;
                const unsigned short* aL_ = bndL + ebOwn;
#pragma unroll 4
                for (int kbl = 0; kbl < 16; ++kbl) {
                    const short8 aH = *(const short8*)(aH_ + kbl * 1024);
                    const short8 aL = *(const short8*)(aL_ + kbl * 1024);
                    const int wo = kbl * 512 + lane * 8;
                    const short8 wH0 = *(const short8*)&wgt[wo];
                    const short8 wL0 = *(const short8*)&wgt[32768 + wo];
                    const short8 wH1 = *(const short8*)&wgt[16384 + wo];
                    const short8 wL1 = *(const short8*)&wgt[49152 + wo];
                    C0 = __builtin_amdgcn_mfma_f32_16x16x32_bf16(aH, wH0, C0, 0, 0, 0);
                    C0 = __builtin_amdgcn_mfma_f32_16x16x32_bf16(aL, wH0, C0, 0, 0, 0);
                    C0 = __builtin_amdgcn_mfma_f32_16x16x32_bf16(aH, wL0, C0, 0, 0, 0);
                    C1 = __builtin_amdgcn_mfma_f32_16x16x32_bf16(aH, wH1, C1, 0, 0, 0);
                    C1 = __builtin_amdgcn_mfma_f32_16x16x32_bf16(aL, wH1, C1, 0, 0, 0);
                    C1 = __builtin_amdgcn_mfma_f32_16x16x32_bf16(aH, wL1, C1, 0, 0, 0);
                }
            }
            // ---- input part: kb slots 16.. ----
            if (l > 0) {
                const size_t ebIn = ((size_t)((l - 1) * 2 + pr) * 8 + bcw) * 16384
                                  + (size_t)mtw * 512 + (size_t)lane * 8;
                const unsigned short* aH_ = bndH + ebIn;
                const unsigned short* aL_ = bndL + ebIn;
#pragma unroll 4
                for (int kbl = 0; kbl < 16; ++kbl) {
                    const short8 aH = *(const short8*)(aH_ + kbl * 1024);
                    const short8 aL = *(const short8*)(aL_ + kbl * 1024);
                    const int wo = (16 + kbl) * 512 + lane * 8;
                    const short8 wH0 = *(const short8*)&wgt[wo];
                    const short8 wL0 = *(const short8*)&wgt[32768 + wo];
                    const short8 wH1 = *(const short8*)&wgt[16384 + wo];
                    const short8 wL1 = *(const short8*)&wgt[49152 + wo];
                    C0 = __builtin_amdgcn_mfma_f32_16x16x32_bf16(aH, wH0, C0, 0, 0, 0);
                    C0 = __builtin_amdgcn_mfma_f32_16x16x32_bf16(aL, wH0, C0, 0, 0, 0);
                    C0 = __builtin_amdgcn_mfma_f32_16x16x32_bf16(aH, wL0, C0, 0, 0, 0);
                    C1 = __builtin_amdgcn_mfma_f32_16x16x32_bf16(aH, wH1, C1, 0, 0, 0);
                    C1 = __builtin_amdgcn_mfma_f32_16x16x32_bf16(aL, wH1, C1, 0, 0, 0);
                    C1 = __builtin_amdgcn_mfma_f32_16x16x32_bf16(aH, wL1, C1, 0, 0, 0);
                }
            } else {
                // x(t) converted on the fly: kb slots 16,17 (kx = kbl*32 + bq*8 + kk)
                const int rowa = bcw * 32 + mtw * 16 + (lane & 15);
                const float* xb = x + ((size_t)rowa * T_ + t) * I_ + ((lane >> 4) << 3);
#pragma unroll
                for (int kbl = 0; kbl < 2; ++kbl) {
                    float xv[8];
                    *(float4*)&xv[0] = *(const float4*)(xb + kbl * 32);
                    *(float4*)&xv[4] = *(const float4*)(xb + kbl * 32 + 4);
                    short8 aH, aL;
#pragma unroll
                    for (int e = 0; e < 8; ++e) {
                        const unsigned short hi = f2bfu(xv[e]);
                        aH[e] = (short)hi;
                        aL[e] = (short)f2bfu(xv[e] - bfu2f(hi));
                    }
                    const int wo = (16 + kbl) * 512 + lane * 8;
                    const short8 wH0 = *(const short8*)&wgt[wo];
                    const short8 wL0 = *(const short8*)&wgt[32768 + wo];
                    const short8 wH1 = *(const short8*)&wgt[16384 + wo];
                    const short8 wL1 = *(const short8*)&wgt[49152 + wo];
                    C0 = __builtin_amdgcn_mfma_f32_16x16x32_bf16(aH, wH0, C0, 0, 0, 0);
                    C0 = __builtin_amdgcn_mfma_f32_16x16x32_bf16(aL, wH0, C0, 0, 0, 0);
                    C0 = __builtin_amdgcn_mfma_f32_16x16x32_bf16(aH, wL0, C0, 0, 0, 0);
                    C1 = __builtin_amdgcn_mfma_f32_16x16x32_bf16(aH, wH1, C1, 0, 0, 0);
                    C1 = __builtin_amdgcn_mfma_f32_16x16x32_bf16(aL, wH1, C1, 0, 0, 0);
                    C1 = __builtin_amdgcn_mfma_f32_16x16x32_bf16(aH, wL1, C1, 0, 0, 0);
                }
            }

            // ---- 4x4 transpose: lane -> (row, unit) with all 4 gates in regs ----
            xpose(C0);
            xpose(C1);

            // ---- gates -> c,h ; write h(t) ----
            const size_t wb = ((size_t)(l * 2 + pw) * 8 + bc2) * 16384;
            {
                const float gi = C0[0] + bias0.x;
                const float gf = C0[1] + bias0.y;
                const float gg = C0[2] + bias0.z;
                const float go = C0[3] + bias0.w;
                const float iv = 1.f / (1.f + expf(-gi));
                const float fv = 1.f / (1.f + expf(-gf));
                const float gv = tanhf(gg);
                const float ov = 1.f / (1.f + expf(-go));
                c0 = fv * c0 + iv * gv;
                const float hv = ov * tanhf(c0);
                const unsigned short hi = f2bfu(hv);
                bndH[wb + eo0] = hi;
                bndL[wb + eo0] = f2bfu(hv - bfu2f(hi));
            }
            {
                const float gi = C1[0] + bias1.x;
                const float gf = C1[1] + bias1.y;
                const float gg = C1[2] + bias1.z;
                const float go = C1[3] + bias1.w;
                const float iv = 1.f / (1.f + expf(-gi));
                const float fv = 1.f / (1.f + expf(-gf));
                const float gv = tanhf(gg);
                const float ov = 1.f / (1.f + expf(-go));
                c1 = fv * c1 + iv * gv;
                const float hv = ov * tanhf(c1);
                const unsigned short hi = f2bfu(hv);
                bndH[wb + eo1] = hi;
                bndL[wb + eo1] = f2bfu(hv - bfu2f(hi));
            }
        }
        grid.sync();
    }
}

// ---------- MLP head: reads h_3[T-1] (parity 0) from bnd frag layout ----------
__global__ __launch_bounds__(128)
void mlp_head(const unsigned short* __restrict__ bndH, const unsigned short* __restrict__ bndL,
              const float* __restrict__ W1, const float* __restrict__ b1,
              const float* __restrict__ W2, const float* __restrict__ b2,
              const float* __restrict__ W3, const float* __restrict__ b3,
              float* __restrict__ out)
{
    __shared__ float hl[H_];
    __shared__ float a1[128];
    __shared__ float a2[64];
    const int b = blockIdx.x, tid = threadIdx.x;
    {
        const int bc = b >> 5, m = b & 31;
        const int mtt = m >> 4, m16 = m & 15;
        const size_t base = ((size_t)48 + bc) * 16384;   // (3*2+0)*8 + bc
        const int k0 = tid << 2;
        const int kb = k0 >> 5, bq = (k0 >> 3) & 3, kk0 = k0 & 7;
        const size_t eo = base + ((size_t)((kb << 1) + mtt) * 64 + (m16 + (bq << 4))) * 8 + kk0;
        const ushort4 vh = *(const ushort4*)(bndH + eo);
        const ushort4 vl = *(const ushort4*)(bndL + eo);
        hl[k0 + 0] = bfu2f(vh.x) + bfu2f(vl.x);
        hl[k0 + 1] = bfu2f(vh.y) + bfu2f(vl.y);
        hl[k0 + 2] = bfu2f(vh.z) + bfu2f(vl.z);
        hl[k0 + 3] = bfu2f(vh.w) + bfu2f(vl.w);
    }
    __syncthreads();
    {
        float s = b1[tid];
        const float* wr = W1 + (size_t)tid * H_;
        for (int k = 0; k < H_; ++k) s = fmaf(wr[k], hl[k], s);
        a1[tid] = fmaxf(s, 0.f);
    }
    __syncthreads();
    if (tid < 64) {
        float s = b2[tid];
        const float* wr = W2 + (tid << 7);
        for (int k = 0; k < 128; ++k) s = fmaf(wr[k], a1[k], s);
        a2[tid] = fmaxf(s, 0.f);
    }
    __syncthreads();
    if (tid < 64) {
        float v = W3[tid] * a2[tid];
        for (int off = 32; off; off >>= 1) v += __shfl_down(v, off);
        if (tid == 0) out[b] = v + b3[0];
    }
}

extern "C" void kernel_launch(void* const* d_in, const int* in_sizes, int n_in,
                              void* d_out, int out_size, void* d_ws, size_t ws_size,
                              hipStream_t stream)
{
    const float* x    = (const float*)d_in[0];
    const float* Wih0 = (const float*)d_in[1];
    const float* WihR = (const float*)d_in[2];
    const float* Whh  = (const float*)d_in[3];
    const float* bih  = (const float*)d_in[4];
    const float* bhh  = (const float*)d_in[5];
    const float* W1   = (const float*)d_in[6];
    const float* b1   = (const float*)d_in[7];
    const float* W2   = (const float*)d_in[8];
    const float* b2   = (const float*)d_in[9];
    const float* W3   = (const float*)d_in[10];
    const float* b3   = (const float*)d_in[11];
    float* out = (float*)d_out;

    const size_t W0e = (size_t)(H_ + I_) * G_;       // 1,179,648 elems (NKB=18)
    const size_t W1e = (size_t)(2 * H_) * G_;        // 2,097,152 elems (NKB=32)
    const size_t biasE = (size_t)L_ * G_;            // 8192
    const size_t bndE  = (size_t)64 * 16384;         // 1,048,576 elems per split

    auto align256 = [](size_t v) { return (v + 255) & ~(size_t)255; };
    const size_t need = 2 * align256(W0e * 2) + 6 * align256(W1e * 2)
                      + align256(biasE * 4) + 2 * align256(bndE * 2);

    char* ws = (char*)d_ws;
    size_t off = 0;
    auto alloc = [&](size_t bytes) -> void* {
        void* p = ws + off;
        off = align256(off + bytes);
        return p;
    };

    if (ws_size < need) {
        sentinel_fill<<<1, 256, 0, stream>>>(out, -11111.0f);
        return;
    }

    unsigned short* WH0 = (unsigned short*)alloc(W0e * 2);
    unsigned short* WL0 = (unsigned short*)alloc(W0e * 2);
    unsigned short* WH1 = (unsigned short*)alloc(W1e * 2);
    unsigned short* WL1 = (unsigned short*)alloc(W1e * 2);
    unsigned short* WH2 = (unsigned short*)alloc(W1e * 2);
    unsigned short* WL2 = (unsigned short*)alloc(W1e * 2);
    unsigned short* WH3 = (unsigned short*)alloc(W1e * 2);
    unsigned short* WL3 = (unsigned short*)alloc(W1e * 2);
    float* biasR = (float*)alloc(biasE * 4);
    unsigned short* bndH = (unsigned short*)alloc(bndE * 2);
    unsigned short* bndL = (unsigned short*)alloc(bndE * 2);

    const size_t WL_ = (size_t)G_ * H_;
    prep_wtfrag<<<1024, 256, 0, stream>>>(Whh + 0 * WL_, Wih0,           I_, 18, WH0, WL0);
    prep_wtfrag<<<1024, 256, 0, stream>>>(Whh + 1 * WL_, WihR + 0 * WL_, H_, 32, WH1, WL1);
    prep_wtfrag<<<1024, 256, 0, stream>>>(Whh + 2 * WL_, WihR + 1 * WL_, H_, 32, WH2, WL2);
    prep_bias<<<(L_ * G_ + 255) / 256, 256, 0, stream>>>(bih, bhh, biasR);
    prep_wtfrag<<<1024, 256, 0, stream>>>(Whh + 3 * WL_, WihR + 2 * WL_, H_, 32, WH3, WL3);
    (void)hipMemsetAsync(bndH, 0, bndE * 2, stream);
    (void)hipMemsetAsync(bndL, 0, bndE * 2, stream);

    {
        (void)hipFuncSetAttribute((const void*)lstm_pipe,
                                  hipFuncAttributeMaxDynamicSharedMemorySize, 131072);
        const float* xa = x;
        const unsigned short *a0 = WH0, *a1 = WL0, *a2 = WH1, *a3 = WL1,
                             *a4 = WH2, *a5 = WL2, *a6 = WH3, *a7 = WL3;
        const float* br = biasR;
        unsigned short *bh = bndH, *bl = bndL;
        void* args[] = { (void*)&xa, (void*)&a0, (void*)&a1, (void*)&a2, (void*)&a3,
                         (void*)&a4, (void*)&a5, (void*)&a6, (void*)&a7,
                         (void*)&br, (void*)&bh, (void*)&bl };
        hipError_t rc = hipLaunchCooperativeKernel((void*)lstm_pipe, dim3(256), dim3(1024),
                                                   args, 131072, stream);
        if (rc != hipSuccess) {
            sentinel_fill<<<1, 256, 0, stream>>>(out, -22222.0f);
            return;
        }
    }

    mlp_head<<<256, 128, 0, stream>>>(bndH, bndL, W1, b1, W2, b2, W3, b3, out);
}